// Round 7
// baseline (188.543 us; speedup 1.0000x reference)
//
#include <hip/hip_runtime.h>
#include <math.h>

#define BATCH    2
#define SEQ      2048
#define DIM      1024
#define HEADS    16
#define HEAD_DIM 64
#define K_NEI    64
#define QKV_DIM  3072
#define MROWS    (BATCH * SEQ)   // 4096
#define ATT_SCALE 0.125f
#define CHUNK    16              // members per chunk = one MFMA M-tile
#define MAXCH    2048            // worst case: all groups singleton

typedef _Float16 half8  __attribute__((ext_vector_type(8)));
typedef _Float16 half4  __attribute__((ext_vector_type(4)));
typedef float    floatx4 __attribute__((ext_vector_type(4)));

__device__ inline void async_copy16(const void* g, void* l) {
  __builtin_amdgcn_global_load_lds(
      (const __attribute__((address_space(1))) unsigned int*)g,
      (__attribute__((address_space(3))) unsigned int*)l, 16, 0, 0);
}

// ---------------------------------------------------------------------------
// fused fp32 -> f16 cast of three tensors + group_map absorbed into blocks 0-7
// ---------------------------------------------------------------------------
__global__ __launch_bounds__(256)
void cast3_group(const float* __restrict__ a, int na4,
                 const float* __restrict__ b, int nb4,
                 const float* __restrict__ c, int nc4,
                 _Float16* __restrict__ oa, _Float16* __restrict__ ob,
                 _Float16* __restrict__ oc,
                 const int* __restrict__ routes, int* __restrict__ gq) {
  if (blockIdx.x < 8) {
    const int q = blockIdx.x * 256 + threadIdx.x;   // 0..2047
    const int lead = routes[q * K_NEI];
    bool same = (lead >= 0) && (lead < SEQ);
    if (same && lead != q) {
      const int4* pa = (const int4*)(routes + q * K_NEI);
      const int4* pb = (const int4*)(routes + lead * K_NEI);
#pragma unroll
      for (int t = 0; t < 16; t++) {
        int4 x = pa[t], y = pb[t];
        same = same && (x.x == y.x) && (x.y == y.y) && (x.z == y.z) && (x.w == y.w);
      }
    }
    gq[q] = same ? lead : q;
  }

  const int total = na4 + nb4 + nc4;
  for (int i = blockIdx.x * blockDim.x + threadIdx.x; i < total;
       i += gridDim.x * blockDim.x) {
    const float* src; _Float16* dst; int idx;
    if (i < na4)            { src = a; dst = oa; idx = i; }
    else if (i < na4 + nb4) { src = b; dst = ob; idx = i - na4; }
    else                    { src = c; dst = oc; idx = i - na4 - nb4; }
    float4 v = *(const float4*)(src + (size_t)idx * 4);
    half4 o;
    o[0] = (_Float16)v.x; o[1] = (_Float16)v.y;
    o[2] = (_Float16)v.z; o[3] = (_Float16)v.w;
    *(half4*)(dst + (size_t)idx * 4) = o;
  }
}

// C[m,n] = sum_k A[m,k]*B[n,k] + bias[n]; A:[M,K] f16, B:[N,K] f16.
// (kept for the output projection; proven config)
template<int BM, int BN, bool HALF_OUT>
__global__ __launch_bounds__(256)
void gemm_bt_f16(const _Float16* __restrict__ A, const _Float16* __restrict__ B,
                 const float* __restrict__ bias, void* __restrict__ Cv,
                 int M, int N, int K) {
  constexpr int FI = BM / 32;
  constexpr int FJ = BN / 32;
  constexpr int CA = BM / 64;
  constexpr int CB = BN / 64;
  __shared__ _Float16 As[2 * BM * 32];
  __shared__ _Float16 Bs[2 * BN * 32];

  const int tid  = threadIdx.x;
  const int lane = tid & 63;
  const int w    = tid >> 6;
  const int wr   = w >> 1;
  const int wc   = w & 1;
  const int bm   = blockIdx.y * BM;
  const int bn   = blockIdx.x * BN;

  const int srow = w * 16 + (lane >> 2);
  const int scol = (lane & 3) * 8;
  const _Float16* ga = A + (size_t)(bm + srow) * K + scol;
  const _Float16* gb = B + (size_t)(bn + srow) * K + scol;

  const int frow = lane & 15;
  const int fk   = (lane >> 4) * 8;

  floatx4 acc[FI][FJ] = {};

  for (int k0 = 0; k0 < K; k0 += 64) {
#pragma unroll
    for (int sub = 0; sub < 2; sub++) {
      const int kk = k0 + sub * 32;
#pragma unroll
      for (int i = 0; i < CA; i++)
        async_copy16(ga + (size_t)(i * 64) * K + kk,
                     As + sub * BM * 32 + w * 512 + i * 2048);
#pragma unroll
      for (int i = 0; i < CB; i++)
        async_copy16(gb + (size_t)(i * 64) * K + kk,
                     Bs + sub * BN * 32 + w * 512 + i * 2048);
    }
    __syncthreads();

#pragma unroll
    for (int sub = 0; sub < 2; sub++) {
      half8 af[FI], bf[FJ];
#pragma unroll
      for (int i = 0; i < FI; i++)
        af[i] = *(const half8*)&As[sub * BM * 32 + (wr * (BM / 2) + i * 16 + frow) * 32 + fk];
#pragma unroll
      for (int j = 0; j < FJ; j++)
        bf[j] = *(const half8*)&Bs[sub * BN * 32 + (wc * (BN / 2) + j * 16 + frow) * 32 + fk];
#pragma unroll
      for (int i = 0; i < FI; i++)
#pragma unroll
        for (int j = 0; j < FJ; j++) {
          if (HALF_OUT)
            acc[i][j] = __builtin_amdgcn_mfma_f32_16x16x32_f16(bf[j], af[i], acc[i][j], 0, 0, 0);
          else
            acc[i][j] = __builtin_amdgcn_mfma_f32_16x16x32_f16(af[i], bf[j], acc[i][j], 0, 0, 0);
        }
    }
    __syncthreads();
  }

  if (HALF_OUT) {
    _Float16* C = (_Float16*)Cv;
    const int mloc = lane & 15;
    const int nloc = (lane >> 4) * 4;
#pragma unroll
    for (int j = 0; j < FJ; j++) {
      const int gcol = bn + wc * (BN / 2) + j * 16 + nloc;
      float4 bj = *(const float4*)(bias + gcol);
#pragma unroll
      for (int i = 0; i < FI; i++) {
        const int grow = bm + wr * (BM / 2) + i * 16 + mloc;
        half4 hv;
        hv[0] = (_Float16)(acc[i][j][0] + bj.x);
        hv[1] = (_Float16)(acc[i][j][1] + bj.y);
        hv[2] = (_Float16)(acc[i][j][2] + bj.z);
        hv[3] = (_Float16)(acc[i][j][3] + bj.w);
        *(half4*)(C + (size_t)grow * N + gcol) = hv;
      }
    }
  } else {
    float* C = (float*)Cv;
    const int crow = (lane >> 4) * 4;
    const int ccol = lane & 15;
#pragma unroll
    for (int j = 0; j < FJ; j++) {
      const int gcol = bn + wc * (BN / 2) + j * 16 + ccol;
      const float bj = bias[gcol];
#pragma unroll
      for (int i = 0; i < FI; i++) {
        const int grow = bm + wr * (BM / 2) + i * 16 + crow;
        float* cp = C + (size_t)grow * N + gcol;
#pragma unroll
        for (int r = 0; r < 4; r++)
          cp[(size_t)r * N] = acc[i][j][r] + bj;
      }
    }
  }
}

// ---------------------------------------------------------------------------
// QKV projection, deep-pipelined 256x256 tile (T3+T4 port, linear LDS).
// 512 thr = 8 waves (2M x 4N), per-wave output 128x64, acc[8][4].
// 2 LDS buffers x 1 K-tile (BK=64) each = 128 KB -> 1 block/CU.
// Per iter: read ks0 frags -> 32 MFMA -> read ks1 frags -> lgkmcnt(0) ->
// barrier (all waves' reads of buf[cur] returned) -> stage tile j+2 into
// buf[cur] -> 32 MFMA -> vmcnt(8) (tile j+1 landed; j+2 stays in flight) ->
// barrier. vmcnt never drains to 0 in the main loop (T4).
// MFMA operand order + epilogue mapping copied from the proven HALF_OUT path.
// ---------------------------------------------------------------------------
__global__ __launch_bounds__(512, 2)
void gemm_qkv_dp(const _Float16* __restrict__ A, const _Float16* __restrict__ B,
                 const float* __restrict__ bias, _Float16* __restrict__ C,
                 int M, int N, int K) {
  __shared__ _Float16 As[2][256 * 64];
  __shared__ _Float16 Bs[2][256 * 64];

  const int tid  = threadIdx.x;
  const int lane = tid & 63;
  const int w    = tid >> 6;
  const int wr   = w >> 2;        // 0..1
  const int wc   = w & 3;         // 0..3
  const int bm   = blockIdx.y * 256;
  const int bn   = blockIdx.x * 256;

  // staging: seg s = tid + i*512 of 2048 (row = s>>3, colseg = s&7), per matrix
  const int srow = tid >> 3;      // 0..63
  const int scs  = tid & 7;
  const _Float16* ga = A + (size_t)(bm + srow) * K + scs * 8;
  const _Float16* gb = B + (size_t)(bn + srow) * K + scs * 8;

  const int frow  = lane & 15;
  const int fk    = (lane >> 4) * 8;
  const int abase = (wr * 128 + frow) * 64 + fk;
  const int bbase = (wc * 64  + frow) * 64 + fk;

  const int NT = K / 64;          // 16

  auto qstage = [&](int buf, int kt) {
    const int kofs = kt * 64;
    _Float16* da = &As[buf][tid * 8];
    _Float16* db = &Bs[buf][tid * 8];
#pragma unroll
    for (int i = 0; i < 4; i++) {
      async_copy16(ga + (size_t)(i * 64) * K + kofs, da + i * 4096);
      async_copy16(gb + (size_t)(i * 64) * K + kofs, db + i * 4096);
    }
  };

  // prologue: tiles 0 and 1 in flight; wait tile 0 only (8 of 16 outstanding)
  qstage(0, 0);
  qstage(1, 1);
  asm volatile("s_waitcnt vmcnt(8)" ::: "memory");
  __builtin_amdgcn_s_barrier();
  __builtin_amdgcn_sched_barrier(0);

  floatx4 acc[8][4] = {};
  int cur = 0;

  for (int j = 0; j < NT; j++) {
    const _Float16* as = As[cur];
    const _Float16* bs = Bs[cur];
    half8 af[8], bf[4];

    // ---- k-slice 0
#pragma unroll
    for (int mi = 0; mi < 8; mi++) af[mi] = *(const half8*)&as[abase + mi * 1024];
#pragma unroll
    for (int ni = 0; ni < 4; ni++) bf[ni] = *(const half8*)&bs[bbase + ni * 1024];
    __builtin_amdgcn_s_setprio(1);
#pragma unroll
    for (int mi = 0; mi < 8; mi++)
#pragma unroll
      for (int ni = 0; ni < 4; ni++)
        acc[mi][ni] = __builtin_amdgcn_mfma_f32_16x16x32_f16(bf[ni], af[mi], acc[mi][ni], 0, 0, 0);
    __builtin_amdgcn_s_setprio(0);

    // ---- k-slice 1 frag reads (issued before the drain below)
#pragma unroll
    for (int mi = 0; mi < 8; mi++) af[mi] = *(const half8*)&as[abase + mi * 1024 + 32];
#pragma unroll
    for (int ni = 0; ni < 4; ni++) bf[ni] = *(const half8*)&bs[bbase + ni * 1024 + 32];

    // all of THIS wave's LDS reads returned; barrier => all waves done with
    // buf[cur]; only then is re-staging into buf[cur] safe.
    asm volatile("s_waitcnt lgkmcnt(0)" ::: "memory");
    __builtin_amdgcn_sched_barrier(0);
    __builtin_amdgcn_s_barrier();
    __builtin_amdgcn_sched_barrier(0);

    if (j + 2 < NT) qstage(cur, j + 2);

    __builtin_amdgcn_s_setprio(1);
#pragma unroll
    for (int mi = 0; mi < 8; mi++)
#pragma unroll
      for (int ni = 0; ni < 4; ni++)
        acc[mi][ni] = __builtin_amdgcn_mfma_f32_16x16x32_f16(bf[ni], af[mi], acc[mi][ni], 0, 0, 0);
    __builtin_amdgcn_s_setprio(0);

    if (j + 1 < NT) {
      if (j + 2 < NT) asm volatile("s_waitcnt vmcnt(8)" ::: "memory");
      else            asm volatile("s_waitcnt vmcnt(0)" ::: "memory");
      __builtin_amdgcn_s_barrier();
      __builtin_amdgcn_sched_barrier(0);
    }
    cur ^= 1;
  }

  // epilogue (mapping identical to proven HALF_OUT path)
  const int mloc = lane & 15;
  const int nloc = (lane >> 4) * 4;
#pragma unroll
  for (int ni = 0; ni < 4; ni++) {
    const int gcol = bn + wc * 64 + ni * 16 + nloc;
    float4 bj = *(const float4*)(bias + gcol);
#pragma unroll
    for (int mi = 0; mi < 8; mi++) {
      const int grow = bm + wr * 128 + mi * 16 + mloc;
      half4 hv;
      hv[0] = (_Float16)(acc[mi][ni][0] + bj.x);
      hv[1] = (_Float16)(acc[mi][ni][1] + bj.y);
      hv[2] = (_Float16)(acc[mi][ni][2] + bj.z);
      hv[3] = (_Float16)(acc[mi][ni][3] + bj.w);
      *(half4*)(C + (size_t)grow * N + gcol) = hv;
    }
  }
}

// ---------------------------------------------------------------------------
// Grouping phase B (1 block, LDS-only)
// ---------------------------------------------------------------------------
__global__ __launch_bounds__(256)
void group_emit(const int* __restrict__ gq, int* __restrict__ gmem,
                int* __restrict__ chunks, int* __restrict__ meta) {
  __shared__ int cnt[SEQ];
  __shared__ int base[SEQ];
  __shared__ int warpsum[8];
  __shared__ int nch_sm;
  const int tid = threadIdx.x;

  for (int i = tid; i < SEQ; i += 256) cnt[i] = 0;
  if (tid == 0) nch_sm = 0;
  __syncthreads();

  for (int q = tid; q < SEQ; q += 256) atomicAdd(&cnt[gq[q]], 1);
  __syncthreads();

  int local[8];
  int s = 0;
#pragma unroll
  for (int k = 0; k < 8; k++) { local[k] = s; s += cnt[tid * 8 + k]; }
  const int lane = tid & 63, wv = tid >> 6;
  int sc = s;
#pragma unroll
  for (int off = 1; off < 64; off <<= 1) {
    int t2 = __shfl_up(sc, off);
    if (lane >= off) sc += t2;
  }
  if (lane == 63) warpsum[wv] = sc;
  __syncthreads();
  int wvoff = 0;
  for (int k = 0; k < wv; k++) wvoff += warpsum[k];
  const int thrbase = wvoff + sc - s;
#pragma unroll
  for (int k = 0; k < 8; k++) base[tid * 8 + k] = thrbase + local[k];
  __syncthreads();

  for (int gg = tid; gg < SEQ; gg += 256) {
    const int c = cnt[gg];
    if (c > 0) {
      const int nchk = (c + CHUNK - 1) / CHUNK;
      const int slot = atomicAdd(&nch_sm, nchk);
      for (int k2 = 0; k2 < nchk; k2++) {
        const int sidx = slot + k2;
        if (sidx < MAXCH) {
          const int len = min(CHUNK, c - k2 * CHUNK);
          chunks[2 * sidx]     = gg;
          chunks[2 * sidx + 1] = (base[gg] + k2 * CHUNK) | (len << 16);
        }
      }
    }
  }
  __syncthreads();
  if (tid == 0) meta[0] = min(nch_sm, MAXCH);

  for (int q = tid; q < SEQ; q += 256) {
    const int slot = atomicAdd(&base[gq[q]], 1);
    gmem[slot] = q;
  }
}

// ---------------------------------------------------------------------------
// MFMA grouped attention — round-6 best-measured kernel, verbatim.
// ---------------------------------------------------------------------------
__global__ __launch_bounds__(128)
void attn_mfma(const _Float16* __restrict__ qkv, const int* __restrict__ routes,
               const int* __restrict__ gmem, const int* __restrict__ chunks,
               const int* __restrict__ meta, _Float16* __restrict__ ao) {
  __shared__ _Float16 lds[2][9216];

  const int tid  = threadIdx.x;
  const int w    = tid >> 6;
  const int lane = tid & 63;
  const int g    = lane >> 4;
  const int c    = lane & 15;

  _Float16* Ks = &lds[w][0];
  _Float16* Vs = &lds[w][4096];
  _Float16* Ps = &lds[w][8192];

  const int nch    = meta[0];
  const int njobs  = nch * 32;
  const int nwaves = gridDim.x * 2;

  const int c8   = (lane & 7) ^ ((lane >> 3) & 7);  // swizzled source segment
  const int rsub = lane >> 3;

  for (int job = blockIdx.x * 2 + w; job < njobs; job += nwaves) {
    const int ch = job >> 5;
    const int bh = job & 31;
    const int h  = bh & 15;
    const int b  = bh >> 4;

    const int gid   = chunks[2 * ch];
    const int mpack = chunks[2 * ch + 1];
    const int mbase = mpack & 0xFFFF;
    const int mlen  = mpack >> 16;
    const size_t rowb = (size_t)b * SEQ;

    const int rt_l = routes[gid * K_NEI + lane];
    const int qm_l = gmem[mbase + min(c, mlen - 1)];

#pragma unroll
    for (int k = 0; k < 8; k++) {
      const int row = __shfl(rt_l, 8 * k + rsub);
      const _Float16* kp = qkv + (rowb + row) * QKV_DIM + DIM + h * HEAD_DIM + c8 * 8;
      async_copy16(kp,       Ks + k * 512);
      async_copy16(kp + DIM, Vs + k * 512);
    }

    const _Float16* qrow = qkv + (rowb + qm_l) * QKV_DIM + h * HEAD_DIM + g * 8;
    const half8 qf0 = *(const half8*)(qrow);
    const half8 qf1 = *(const half8*)(qrow + 32);

    asm volatile("s_waitcnt vmcnt(0)" ::: "memory");

    floatx4 st[4] = {};
    const half8 qf[2] = { qf0, qf1 };
    __builtin_amdgcn_s_setprio(1);
#pragma unroll
    for (int s2 = 0; s2 < 2; s2++) {
#pragma unroll
      for (int m = 0; m < 4; m++) {
        const int r = m * 16 + c;
        const half8 kf =
            *(const half8*)&Ks[r * 64 + ((((s2 << 2) + g) ^ (c & 7)) << 3)];
        st[m] = __builtin_amdgcn_mfma_f32_16x16x32_f16(kf, qf[s2], st[m], 0, 0, 0);
      }
    }
    __builtin_amdgcn_s_setprio(0);

    float mx = st[0][0];
#pragma unroll
    for (int m = 0; m < 4; m++)
#pragma unroll
      for (int r = 0; r < 4; r++) mx = fmaxf(mx, st[m][r]);
    mx = fmaxf(mx, __shfl_xor(mx, 16));
    mx = fmaxf(mx, __shfl_xor(mx, 32));

    float p[16];
    float sum = 0.f;
#pragma unroll
    for (int m = 0; m < 4; m++)
#pragma unroll
      for (int r = 0; r < 4; r++) {
        const float e = __expf((st[m][r] - mx) * ATT_SCALE);
        p[m * 4 + r] = e;
        sum += e;
      }
    sum += __shfl_xor(sum, 16);
    sum += __shfl_xor(sum, 32);
    const float inv = 1.0f / sum;

#pragma unroll
    for (int m = 0; m < 4; m++) {
      half4 ph;
      ph[0] = (_Float16)(p[m * 4 + 0] * inv);
      ph[1] = (_Float16)(p[m * 4 + 1] * inv);
      ph[2] = (_Float16)(p[m * 4 + 2] * inv);
      ph[3] = (_Float16)(p[m * 4 + 3] * inv);
      const int idx = c * 64 + (((2 * m + (g >> 1)) ^ (c & 7)) << 3) + ((g & 1) << 2);
      *(half4*)&Ps[idx] = ph;
    }
    asm volatile("s_waitcnt lgkmcnt(0)" ::: "memory");

    half8 pf[2];
#pragma unroll
    for (int s2 = 0; s2 < 2; s2++)
      pf[s2] = *(const half8*)&Ps[c * 64 + ((((s2 << 2) + g) ^ (c & 7)) << 3)];

    floatx4 oa[4] = {};
    __builtin_amdgcn_s_setprio(1);
#pragma unroll
    for (int n = 0; n < 4; n++) {
      const int dtop = 2 * n + (c >> 3);
#pragma unroll
      for (int s2 = 0; s2 < 2; s2++) {
        half8 vf;
#pragma unroll
        for (int j = 0; j < 8; j++) {
          const int rr = s2 * 32 + g * 8 + j;          // rr & 7 == j
          vf[j] = Vs[rr * 64 + ((dtop ^ j) << 3) + (c & 7)];
        }
        oa[n] = __builtin_amdgcn_mfma_f32_16x16x32_f16(pf[s2], vf, oa[n], 0, 0, 0);
      }
    }
    __builtin_amdgcn_s_setprio(0);

#pragma unroll
    for (int r = 0; r < 4; r++) {
      const int i = g * 4 + r;
      const int qrow_i = __shfl(qm_l, i);
      if (i < mlen) {
        _Float16* op = ao + (rowb + qrow_i) * DIM + h * HEAD_DIM + c;
#pragma unroll
        for (int n = 0; n < 4; n++) op[n * 16] = (_Float16)oa[n][r];
      }
    }
  }
}

extern "C" void kernel_launch(void* const* d_in, const int* in_sizes, int n_in,
                              void* d_out, int out_size, void* d_ws, size_t ws_size,
                              hipStream_t stream) {
  const float* x      = (const float*)d_in[0];
  const int*   routes = (const int*)  d_in[1];
  const float* qkv_w  = (const float*)d_in[2];
  const float* qkv_b  = (const float*)d_in[3];
  const float* out_w  = (const float*)d_in[4];
  const float* out_b  = (const float*)d_in[5];
  float* out = (float*)d_out;

  _Float16* qkvh = (_Float16*)d_ws;                       // 4096*3072
  _Float16* aoh  = qkvh + (size_t)MROWS * QKV_DIM;        // 4096*1024
  _Float16* xh   = aoh  + (size_t)MROWS * DIM;            // 4096*1024
  _Float16* wh   = xh   + (size_t)MROWS * DIM;            // 3072*1024
  _Float16* owh  = wh   + (size_t)QKV_DIM * DIM;          // 1024*1024

  // Grouping scratch in the tail of d_out (consumed by attn, then fully
  // overwritten by the output-projection GEMM).
  char* scr   = (char*)d_out + (size_t)out_size - 65536;
  int* gq     = (int*)scr;            // 2048 ints
  int* gmem   = gq + SEQ;             // 2048 ints (member list, CSR order)
  int* chunks = gmem + SEQ;           // 2*MAXCH ints
  int* meta   = chunks + 2 * MAXCH;   // nchunks

  // cast + group_map fused (blocks 0-7 also write gq)
  cast3_group<<<1024, 256, 0, stream>>>(x, MROWS * DIM / 4,
                                        qkv_w, QKV_DIM * DIM / 4,
                                        out_w, DIM * DIM / 4,
                                        xh, wh, owh, routes, gq);

  group_emit<<<1, 256, 0, stream>>>(gq, gmem, chunks, meta);

  // QKV projection: deep-pipelined 256x256 tile, 192 blocks
  {
    dim3 g(QKV_DIM / 256, MROWS / 256);
    gemm_qkv_dp<<<g, 512, 0, stream>>>(xh, wh, qkv_b, qkvh,
                                       MROWS, QKV_DIM, DIM);
  }

  attn_mfma<<<4096, 128, 0, stream>>>(qkvh, routes, gmem, chunks, meta, aoh);

  // output projection: 64x128 tile, 512 blocks
  {
    dim3 g(DIM / 128, MROWS / 64);
    gemm_bt_f16<64, 128, false><<<g, 256, 0, stream>>>(aoh, owh, out_b, out,
                                                       MROWS, DIM, DIM);
  }
}

// Round 8
// 176.564 us; speedup vs baseline: 1.0678x; 1.0678x over previous
//
#include <hip/hip_runtime.h>
#include <math.h>

#define BATCH    2
#define SEQ      2048
#define DIM      1024
#define HEADS    16
#define HEAD_DIM 64
#define K_NEI    64
#define QKV_DIM  3072
#define MROWS    (BATCH * SEQ)   // 4096
#define ATT_SCALE 0.125f
#define CHUNK    16              // members per chunk = one MFMA M-tile
#define MAXCH    2048            // worst case: all groups singleton

typedef _Float16 half8  __attribute__((ext_vector_type(8)));
typedef _Float16 half4  __attribute__((ext_vector_type(4)));
typedef float    floatx4 __attribute__((ext_vector_type(4)));

__device__ inline void async_copy16(const void* g, void* l) {
  __builtin_amdgcn_global_load_lds(
      (const __attribute__((address_space(1))) unsigned int*)g,
      (__attribute__((address_space(3))) unsigned int*)l, 16, 0, 0);
}

// ---------------------------------------------------------------------------
// fused fp32 -> f16 cast of three tensors + group_map absorbed into blocks 0-7
// ---------------------------------------------------------------------------
__global__ __launch_bounds__(256)
void cast3_group(const float* __restrict__ a, int na4,
                 const float* __restrict__ b, int nb4,
                 const float* __restrict__ c, int nc4,
                 _Float16* __restrict__ oa, _Float16* __restrict__ ob,
                 _Float16* __restrict__ oc,
                 const int* __restrict__ routes, int* __restrict__ gq) {
  if (blockIdx.x < 8) {
    const int q = blockIdx.x * 256 + threadIdx.x;   // 0..2047
    const int lead = routes[q * K_NEI];
    bool same = (lead >= 0) && (lead < SEQ);
    if (same && lead != q) {
      const int4* pa = (const int4*)(routes + q * K_NEI);
      const int4* pb = (const int4*)(routes + lead * K_NEI);
#pragma unroll
      for (int t = 0; t < 16; t++) {
        int4 x = pa[t], y = pb[t];
        same = same && (x.x == y.x) && (x.y == y.y) && (x.z == y.z) && (x.w == y.w);
      }
    }
    gq[q] = same ? lead : q;
  }

  const int total = na4 + nb4 + nc4;
  for (int i = blockIdx.x * blockDim.x + threadIdx.x; i < total;
       i += gridDim.x * blockDim.x) {
    const float* src; _Float16* dst; int idx;
    if (i < na4)            { src = a; dst = oa; idx = i; }
    else if (i < na4 + nb4) { src = b; dst = ob; idx = i - na4; }
    else                    { src = c; dst = oc; idx = i - na4 - nb4; }
    float4 v = *(const float4*)(src + (size_t)idx * 4);
    half4 o;
    o[0] = (_Float16)v.x; o[1] = (_Float16)v.y;
    o[2] = (_Float16)v.z; o[3] = (_Float16)v.w;
    *(half4*)(dst + (size_t)idx * 4) = o;
  }
}

// C[m,n] = sum_k A[m,k]*B[n,k] + bias[n]; A:[M,K] f16, B:[N,K] f16.
// (kept for the output projection; proven config)
template<int BM, int BN, bool HALF_OUT>
__global__ __launch_bounds__(256)
void gemm_bt_f16(const _Float16* __restrict__ A, const _Float16* __restrict__ B,
                 const float* __restrict__ bias, void* __restrict__ Cv,
                 int M, int N, int K) {
  constexpr int FI = BM / 32;
  constexpr int FJ = BN / 32;
  constexpr int CA = BM / 64;
  constexpr int CB = BN / 64;
  __shared__ _Float16 As[2 * BM * 32];
  __shared__ _Float16 Bs[2 * BN * 32];

  const int tid  = threadIdx.x;
  const int lane = tid & 63;
  const int w    = tid >> 6;
  const int wr   = w >> 1;
  const int wc   = w & 1;
  const int bm   = blockIdx.y * BM;
  const int bn   = blockIdx.x * BN;

  const int srow = w * 16 + (lane >> 2);
  const int scol = (lane & 3) * 8;
  const _Float16* ga = A + (size_t)(bm + srow) * K + scol;
  const _Float16* gb = B + (size_t)(bn + srow) * K + scol;

  const int frow = lane & 15;
  const int fk   = (lane >> 4) * 8;

  floatx4 acc[FI][FJ] = {};

  for (int k0 = 0; k0 < K; k0 += 64) {
#pragma unroll
    for (int sub = 0; sub < 2; sub++) {
      const int kk = k0 + sub * 32;
#pragma unroll
      for (int i = 0; i < CA; i++)
        async_copy16(ga + (size_t)(i * 64) * K + kk,
                     As + sub * BM * 32 + w * 512 + i * 2048);
#pragma unroll
      for (int i = 0; i < CB; i++)
        async_copy16(gb + (size_t)(i * 64) * K + kk,
                     Bs + sub * BN * 32 + w * 512 + i * 2048);
    }
    __syncthreads();

#pragma unroll
    for (int sub = 0; sub < 2; sub++) {
      half8 af[FI], bf[FJ];
#pragma unroll
      for (int i = 0; i < FI; i++)
        af[i] = *(const half8*)&As[sub * BM * 32 + (wr * (BM / 2) + i * 16 + frow) * 32 + fk];
#pragma unroll
      for (int j = 0; j < FJ; j++)
        bf[j] = *(const half8*)&Bs[sub * BN * 32 + (wc * (BN / 2) + j * 16 + frow) * 32 + fk];
#pragma unroll
      for (int i = 0; i < FI; i++)
#pragma unroll
        for (int j = 0; j < FJ; j++) {
          if (HALF_OUT)
            acc[i][j] = __builtin_amdgcn_mfma_f32_16x16x32_f16(bf[j], af[i], acc[i][j], 0, 0, 0);
          else
            acc[i][j] = __builtin_amdgcn_mfma_f32_16x16x32_f16(af[i], bf[j], acc[i][j], 0, 0, 0);
        }
    }
    __syncthreads();
  }

  if (HALF_OUT) {
    _Float16* C = (_Float16*)Cv;
    const int mloc = lane & 15;
    const int nloc = (lane >> 4) * 4;
#pragma unroll
    for (int j = 0; j < FJ; j++) {
      const int gcol = bn + wc * (BN / 2) + j * 16 + nloc;
      float4 bj = *(const float4*)(bias + gcol);
#pragma unroll
      for (int i = 0; i < FI; i++) {
        const int grow = bm + wr * (BM / 2) + i * 16 + mloc;
        half4 hv;
        hv[0] = (_Float16)(acc[i][j][0] + bj.x);
        hv[1] = (_Float16)(acc[i][j][1] + bj.y);
        hv[2] = (_Float16)(acc[i][j][2] + bj.z);
        hv[3] = (_Float16)(acc[i][j][3] + bj.w);
        *(half4*)(C + (size_t)grow * N + gcol) = hv;
      }
    }
  } else {
    float* C = (float*)Cv;
    const int crow = (lane >> 4) * 4;
    const int ccol = lane & 15;
#pragma unroll
    for (int j = 0; j < FJ; j++) {
      const int gcol = bn + wc * (BN / 2) + j * 16 + ccol;
      const float bj = bias[gcol];
#pragma unroll
      for (int i = 0; i < FI; i++) {
        const int grow = bm + wr * (BM / 2) + i * 16 + crow;
        float* cp = C + (size_t)grow * N + gcol;
#pragma unroll
        for (int r = 0; r < 4; r++)
          cp[(size_t)r * N] = acc[i][j][r] + bj;
      }
    }
  }
}

// ---------------------------------------------------------------------------
// QKV projection, deep-pipelined 256x256 tile + T2 XOR swizzle.
// Round-7 schedule verbatim (it passed; vmcnt protocol proven); the ONLY
// change is bank-conflict elimination per rule #21:
//   - LDS dest stays linear (global_load_lds requirement);
//   - global SOURCE seg = scs ^ (srow&7)  (rows step by 64 == 0 mod 8, so
//     one XOR serves all 4 row-copies);
//   - READ seg' = seg ^ (frow&7)  (same involution).
// Round-7 measured 16-way conflict (7.08M cycles, 12 extra cyc/read); after
// swizzle lanes 0-7 hit 8 distinct 16B slots (all 32 banks), lanes 8-15
// repeat 1024B higher (bank-congruent) -> free 2-way.
// ---------------------------------------------------------------------------
__global__ __launch_bounds__(512, 2)
void gemm_qkv_dp(const _Float16* __restrict__ A, const _Float16* __restrict__ B,
                 const float* __restrict__ bias, _Float16* __restrict__ C,
                 int M, int N, int K) {
  __shared__ _Float16 As[2][256 * 64];
  __shared__ _Float16 Bs[2][256 * 64];

  const int tid  = threadIdx.x;
  const int lane = tid & 63;
  const int w    = tid >> 6;
  const int wr   = w >> 2;        // 0..1
  const int wc   = w & 3;         // 0..3
  const int bm   = blockIdx.y * 256;
  const int bn   = blockIdx.x * 256;

  // staging: dest seg (srow, scs) holds global seg (srow, scs ^ (srow&7))
  const int srow = tid >> 3;      // 0..63
  const int scs  = tid & 7;
  const int sseg = scs ^ (srow & 7);
  const _Float16* ga = A + (size_t)(bm + srow) * K + sseg * 8;
  const _Float16* gb = B + (size_t)(bn + srow) * K + sseg * 8;

  const int frow = lane & 15;
  const int sw   = frow & 7;
  const int s0   = ((lane >> 4)    ) ^ sw;   // read slot, k-slice 0
  const int s1   = ((lane >> 4) + 4) ^ sw;   // read slot, k-slice 1
  const int abase = (wr * 128 + frow) * 64;
  const int bbase = (wc * 64  + frow) * 64;

  const int NT = K / 64;          // 16

  auto qstage = [&](int buf, int kt) {
    const int kofs = kt * 64;
    _Float16* da = &As[buf][tid * 8];
    _Float16* db = &Bs[buf][tid * 8];
#pragma unroll
    for (int i = 0; i < 4; i++) {
      async_copy16(ga + (size_t)(i * 64) * K + kofs, da + i * 4096);
      async_copy16(gb + (size_t)(i * 64) * K + kofs, db + i * 4096);
    }
  };

  // prologue: tiles 0 and 1 in flight; wait tile 0 only (8 of 16 outstanding)
  qstage(0, 0);
  qstage(1, 1);
  asm volatile("s_waitcnt vmcnt(8)" ::: "memory");
  __builtin_amdgcn_s_barrier();
  __builtin_amdgcn_sched_barrier(0);

  floatx4 acc[8][4] = {};
  int cur = 0;

  for (int j = 0; j < NT; j++) {
    const _Float16* as = As[cur];
    const _Float16* bs = Bs[cur];
    half8 af[8], bf[4];

    // ---- k-slice 0 (swizzled slot s0)
#pragma unroll
    for (int mi = 0; mi < 8; mi++) af[mi] = *(const half8*)&as[abase + mi * 1024 + s0 * 8];
#pragma unroll
    for (int ni = 0; ni < 4; ni++) bf[ni] = *(const half8*)&bs[bbase + ni * 1024 + s0 * 8];
    __builtin_amdgcn_s_setprio(1);
#pragma unroll
    for (int mi = 0; mi < 8; mi++)
#pragma unroll
      for (int ni = 0; ni < 4; ni++)
        acc[mi][ni] = __builtin_amdgcn_mfma_f32_16x16x32_f16(bf[ni], af[mi], acc[mi][ni], 0, 0, 0);
    __builtin_amdgcn_s_setprio(0);

    // ---- k-slice 1 frag reads (swizzled slot s1), issued before the drain
#pragma unroll
    for (int mi = 0; mi < 8; mi++) af[mi] = *(const half8*)&as[abase + mi * 1024 + s1 * 8];
#pragma unroll
    for (int ni = 0; ni < 4; ni++) bf[ni] = *(const half8*)&bs[bbase + ni * 1024 + s1 * 8];

    // all of THIS wave's LDS reads returned; barrier => all waves done with
    // buf[cur]; only then is re-staging into buf[cur] safe.
    asm volatile("s_waitcnt lgkmcnt(0)" ::: "memory");
    __builtin_amdgcn_sched_barrier(0);
    __builtin_amdgcn_s_barrier();
    __builtin_amdgcn_sched_barrier(0);

    if (j + 2 < NT) qstage(cur, j + 2);

    __builtin_amdgcn_s_setprio(1);
#pragma unroll
    for (int mi = 0; mi < 8; mi++)
#pragma unroll
      for (int ni = 0; ni < 4; ni++)
        acc[mi][ni] = __builtin_amdgcn_mfma_f32_16x16x32_f16(bf[ni], af[mi], acc[mi][ni], 0, 0, 0);
    __builtin_amdgcn_s_setprio(0);

    if (j + 1 < NT) {
      if (j + 2 < NT) asm volatile("s_waitcnt vmcnt(8)" ::: "memory");
      else            asm volatile("s_waitcnt vmcnt(0)" ::: "memory");
      __builtin_amdgcn_s_barrier();
      __builtin_amdgcn_sched_barrier(0);
    }
    cur ^= 1;
  }

  // epilogue (mapping identical to proven HALF_OUT path)
  const int mloc = lane & 15;
  const int nloc = (lane >> 4) * 4;
#pragma unroll
  for (int ni = 0; ni < 4; ni++) {
    const int gcol = bn + wc * 64 + ni * 16 + nloc;
    float4 bj = *(const float4*)(bias + gcol);
#pragma unroll
    for (int mi = 0; mi < 8; mi++) {
      const int grow = bm + wr * 128 + mi * 16 + mloc;
      half4 hv;
      hv[0] = (_Float16)(acc[mi][ni][0] + bj.x);
      hv[1] = (_Float16)(acc[mi][ni][1] + bj.y);
      hv[2] = (_Float16)(acc[mi][ni][2] + bj.z);
      hv[3] = (_Float16)(acc[mi][ni][3] + bj.w);
      *(half4*)(C + (size_t)grow * N + gcol) = hv;
    }
  }
}

// ---------------------------------------------------------------------------
// Grouping phase B (1 block, LDS-only)
// ---------------------------------------------------------------------------
__global__ __launch_bounds__(256)
void group_emit(const int* __restrict__ gq, int* __restrict__ gmem,
                int* __restrict__ chunks, int* __restrict__ meta) {
  __shared__ int cnt[SEQ];
  __shared__ int base[SEQ];
  __shared__ int warpsum[8];
  __shared__ int nch_sm;
  const int tid = threadIdx.x;

  for (int i = tid; i < SEQ; i += 256) cnt[i] = 0;
  if (tid == 0) nch_sm = 0;
  __syncthreads();

  for (int q = tid; q < SEQ; q += 256) atomicAdd(&cnt[gq[q]], 1);
  __syncthreads();

  int local[8];
  int s = 0;
#pragma unroll
  for (int k = 0; k < 8; k++) { local[k] = s; s += cnt[tid * 8 + k]; }
  const int lane = tid & 63, wv = tid >> 6;
  int sc = s;
#pragma unroll
  for (int off = 1; off < 64; off <<= 1) {
    int t2 = __shfl_up(sc, off);
    if (lane >= off) sc += t2;
  }
  if (lane == 63) warpsum[wv] = sc;
  __syncthreads();
  int wvoff = 0;
  for (int k = 0; k < wv; k++) wvoff += warpsum[k];
  const int thrbase = wvoff + sc - s;
#pragma unroll
  for (int k = 0; k < 8; k++) base[tid * 8 + k] = thrbase + local[k];
  __syncthreads();

  for (int gg = tid; gg < SEQ; gg += 256) {
    const int c = cnt[gg];
    if (c > 0) {
      const int nchk = (c + CHUNK - 1) / CHUNK;
      const int slot = atomicAdd(&nch_sm, nchk);
      for (int k2 = 0; k2 < nchk; k2++) {
        const int sidx = slot + k2;
        if (sidx < MAXCH) {
          const int len = min(CHUNK, c - k2 * CHUNK);
          chunks[2 * sidx]     = gg;
          chunks[2 * sidx + 1] = (base[gg] + k2 * CHUNK) | (len << 16);
        }
      }
    }
  }
  __syncthreads();
  if (tid == 0) meta[0] = min(nch_sm, MAXCH);

  for (int q = tid; q < SEQ; q += 256) {
    const int slot = atomicAdd(&base[gq[q]], 1);
    gmem[slot] = q;
  }
}

// ---------------------------------------------------------------------------
// MFMA grouped attention — round-6 best-measured kernel, verbatim.
// ---------------------------------------------------------------------------
__global__ __launch_bounds__(128)
void attn_mfma(const _Float16* __restrict__ qkv, const int* __restrict__ routes,
               const int* __restrict__ gmem, const int* __restrict__ chunks,
               const int* __restrict__ meta, _Float16* __restrict__ ao) {
  __shared__ _Float16 lds[2][9216];

  const int tid  = threadIdx.x;
  const int w    = tid >> 6;
  const int lane = tid & 63;
  const int g    = lane >> 4;
  const int c    = lane & 15;

  _Float16* Ks = &lds[w][0];
  _Float16* Vs = &lds[w][4096];
  _Float16* Ps = &lds[w][8192];

  const int nch    = meta[0];
  const int njobs  = nch * 32;
  const int nwaves = gridDim.x * 2;

  const int c8   = (lane & 7) ^ ((lane >> 3) & 7);  // swizzled source segment
  const int rsub = lane >> 3;

  for (int job = blockIdx.x * 2 + w; job < njobs; job += nwaves) {
    const int ch = job >> 5;
    const int bh = job & 31;
    const int h  = bh & 15;
    const int b  = bh >> 4;

    const int gid   = chunks[2 * ch];
    const int mpack = chunks[2 * ch + 1];
    const int mbase = mpack & 0xFFFF;
    const int mlen  = mpack >> 16;
    const size_t rowb = (size_t)b * SEQ;

    const int rt_l = routes[gid * K_NEI + lane];
    const int qm_l = gmem[mbase + min(c, mlen - 1)];

#pragma unroll
    for (int k = 0; k < 8; k++) {
      const int row = __shfl(rt_l, 8 * k + rsub);
      const _Float16* kp = qkv + (rowb + row) * QKV_DIM + DIM + h * HEAD_DIM + c8 * 8;
      async_copy16(kp,       Ks + k * 512);
      async_copy16(kp + DIM, Vs + k * 512);
    }

    const _Float16* qrow = qkv + (rowb + qm_l) * QKV_DIM + h * HEAD_DIM + g * 8;
    const half8 qf0 = *(const half8*)(qrow);
    const half8 qf1 = *(const half8*)(qrow + 32);

    asm volatile("s_waitcnt vmcnt(0)" ::: "memory");

    floatx4 st[4] = {};
    const half8 qf[2] = { qf0, qf1 };
    __builtin_amdgcn_s_setprio(1);
#pragma unroll
    for (int s2 = 0; s2 < 2; s2++) {
#pragma unroll
      for (int m = 0; m < 4; m++) {
        const int r = m * 16 + c;
        const half8 kf =
            *(const half8*)&Ks[r * 64 + ((((s2 << 2) + g) ^ (c & 7)) << 3)];
        st[m] = __builtin_amdgcn_mfma_f32_16x16x32_f16(kf, qf[s2], st[m], 0, 0, 0);
      }
    }
    __builtin_amdgcn_s_setprio(0);

    float mx = st[0][0];
#pragma unroll
    for (int m = 0; m < 4; m++)
#pragma unroll
      for (int r = 0; r < 4; r++) mx = fmaxf(mx, st[m][r]);
    mx = fmaxf(mx, __shfl_xor(mx, 16));
    mx = fmaxf(mx, __shfl_xor(mx, 32));

    float p[16];
    float sum = 0.f;
#pragma unroll
    for (int m = 0; m < 4; m++)
#pragma unroll
      for (int r = 0; r < 4; r++) {
        const float e = __expf((st[m][r] - mx) * ATT_SCALE);
        p[m * 4 + r] = e;
        sum += e;
      }
    sum += __shfl_xor(sum, 16);
    sum += __shfl_xor(sum, 32);
    const float inv = 1.0f / sum;

#pragma unroll
    for (int m = 0; m < 4; m++) {
      half4 ph;
      ph[0] = (_Float16)(p[m * 4 + 0] * inv);
      ph[1] = (_Float16)(p[m * 4 + 1] * inv);
      ph[2] = (_Float16)(p[m * 4 + 2] * inv);
      ph[3] = (_Float16)(p[m * 4 + 3] * inv);
      const int idx = c * 64 + (((2 * m + (g >> 1)) ^ (c & 7)) << 3) + ((g & 1) << 2);
      *(half4*)&Ps[idx] = ph;
    }
    asm volatile("s_waitcnt lgkmcnt(0)" ::: "memory");

    half8 pf[2];
#pragma unroll
    for (int s2 = 0; s2 < 2; s2++)
      pf[s2] = *(const half8*)&Ps[c * 64 + ((((s2 << 2) + g) ^ (c & 7)) << 3)];

    floatx4 oa[4] = {};
    __builtin_amdgcn_s_setprio(1);
#pragma unroll
    for (int n = 0; n < 4; n++) {
      const int dtop = 2 * n + (c >> 3);
#pragma unroll
      for (int s2 = 0; s2 < 2; s2++) {
        half8 vf;
#pragma unroll
        for (int j = 0; j < 8; j++) {
          const int rr = s2 * 32 + g * 8 + j;          // rr & 7 == j
          vf[j] = Vs[rr * 64 + ((dtop ^ j) << 3) + (c & 7)];
        }
        oa[n] = __builtin_amdgcn_mfma_f32_16x16x32_f16(pf[s2], vf, oa[n], 0, 0, 0);
      }
    }
    __builtin_amdgcn_s_setprio(0);

#pragma unroll
    for (int r = 0; r < 4; r++) {
      const int i = g * 4 + r;
      const int qrow_i = __shfl(qm_l, i);
      if (i < mlen) {
        _Float16* op = ao + (rowb + qrow_i) * DIM + h * HEAD_DIM + c;
#pragma unroll
        for (int n = 0; n < 4; n++) op[n * 16] = (_Float16)oa[n][r];
      }
    }
  }
}

extern "C" void kernel_launch(void* const* d_in, const int* in_sizes, int n_in,
                              void* d_out, int out_size, void* d_ws, size_t ws_size,
                              hipStream_t stream) {
  const float* x      = (const float*)d_in[0];
  const int*   routes = (const int*)  d_in[1];
  const float* qkv_w  = (const float*)d_in[2];
  const float* qkv_b  = (const float*)d_in[3];
  const float* out_w  = (const float*)d_in[4];
  const float* out_b  = (const float*)d_in[5];
  float* out = (float*)d_out;

  _Float16* qkvh = (_Float16*)d_ws;                       // 4096*3072
  _Float16* aoh  = qkvh + (size_t)MROWS * QKV_DIM;        // 4096*1024
  _Float16* xh   = aoh  + (size_t)MROWS * DIM;            // 4096*1024
  _Float16* wh   = xh   + (size_t)MROWS * DIM;            // 3072*1024
  _Float16* owh  = wh   + (size_t)QKV_DIM * DIM;          // 1024*1024

  // Grouping scratch in the tail of d_out (consumed by attn, then fully
  // overwritten by the output-projection GEMM).
  char* scr   = (char*)d_out + (size_t)out_size - 65536;
  int* gq     = (int*)scr;            // 2048 ints
  int* gmem   = gq + SEQ;             // 2048 ints (member list, CSR order)
  int* chunks = gmem + SEQ;           // 2*MAXCH ints
  int* meta   = chunks + 2 * MAXCH;   // nchunks

  // cast + group_map fused (blocks 0-7 also write gq)
  cast3_group<<<1024, 256, 0, stream>>>(x, MROWS * DIM / 4,
                                        qkv_w, QKV_DIM * DIM / 4,
                                        out_w, DIM * DIM / 4,
                                        xh, wh, owh, routes, gq);

  group_emit<<<1, 256, 0, stream>>>(gq, gmem, chunks, meta);

  // QKV projection: deep-pipelined 256x256 tile + T2 swizzle, 192 blocks
  {
    dim3 g(QKV_DIM / 256, MROWS / 256);
    gemm_qkv_dp<<<g, 512, 0, stream>>>(xh, wh, qkv_b, qkvh,
                                       MROWS, QKV_DIM, DIM);
  }

  attn_mfma<<<4096, 128, 0, stream>>>(qkvh, routes, gmem, chunks, meta, aoh);

  // output projection: 64x128 tile, 512 blocks
  {
    dim3 g(DIM / 128, MROWS / 64);
    gemm_bt_f16<64, 128, false><<<g, 256, 0, stream>>>(aoh, owh, out_b, out,
                                                       MROWS, DIM, DIM);
  }
}